// Round 3
// baseline (62.757 us; speedup 1.0000x reference)
//
#include <hip/hip_runtime.h>
#include <math.h>

#define NQ 9
#define NREPS 2
#define NB 512            // 2^NQ amplitudes
#define NSIMS (16*28*28)  // 12544  (= 196 * 64 exactly)

// ---------------- compile-time GF(2) linear algebra of the CNOT ring ----------------
__host__ __device__ constexpr int csigma(int b) {
    for (int c = NQ - 1; c >= 0; --c) {
        const int t  = (c + 1) % NQ;
        const int pc = NQ - 1 - c;
        const int pt = NQ - 1 - t;
        b ^= ((b >> pc) & 1) << pt;
    }
    return b;
}
__host__ __device__ constexpr int csig2(int b) { return csigma(csigma(b)); }

__host__ __device__ constexpr int PIOF(int i)  { return NQ - 1 - i; }
__host__ __device__ constexpr int VMASK(int i) { return csig2(1 << PIOF(i)); }
__host__ __device__ constexpr int SCOMP(int i) { return (~VMASK(i)) & ((1 << NQ) - 1); }
__host__ __device__ constexpr int NV(int i)    { int m = SCOMP(i), c = 0; while (m) { c += m & 1; m >>= 1; } return c; }
__host__ __device__ constexpr int POSI(int i, int t) {
    int m = SCOMP(i), p = 0;
    while (true) { if (m & 1) { if (t == 0) return p; --t; } m >>= 1; ++p; }
}

constexpr int COLC[NQ] = {
    csig2(1 << 0), csig2(1 << 1), csig2(1 << 2), csig2(1 << 3), csig2(1 << 4),
    csig2(1 << 5), csig2(1 << 6), csig2(1 << 7), csig2(1 << 8)
};

// ---- compile-time inverse gather permutation: (qubit i, WHT index w8) -> coef slot u ----
// W_i is indexed by J subset of SCOMP(i); J deposited LSB-first from u. MJ = sigma2^T(J);
// bit Pi of MJ is provably 0 (J disjoint from VMASK(i)); w8 = MJ with bit Pi dropped.
struct InvTab { unsigned short v[NQ][256]; };
__host__ __device__ constexpr InvTab make_inv() {
    InvTab t{};
    for (int i = 0; i < NQ; ++i)
        for (int y = 0; y < 256; ++y) t.v[i][y] = 0xFFFF;
    for (int i = 0; i < NQ; ++i) {
        const int Pi = NQ - 1 - i;
        for (int u = 0; u < (1 << NV(i)); ++u) {
            int sc = SCOMP(i), J = 0, uu = u;
            while (sc) { const int low = sc & (-sc); if (uu & 1) J |= low; sc &= sc - 1; uu >>= 1; }
            int MJ = 0;
            for (int k = 0; k < NQ; ++k) {
                int x = COLC[k] & J, p = 0;
                while (x) { p ^= x & 1; x >>= 1; }
                MJ |= p << k;
            }
            const int w8 = ((MJ >> (Pi + 1)) << Pi) | (MJ & ((1 << Pi) - 1));
            t.v[i][w8] = (unsigned short)u;
        }
    }
    return t;
}
__device__ constexpr InvTab INVTAB = make_inv();

// ---------------- cross-lane helpers (verified on this HW in the round-0 kernel) ----------------
template<int CTRL>
__device__ __forceinline__ float dppmov(float x) {
    return __int_as_float(__builtin_amdgcn_update_dpp(
        0, __float_as_int(x), CTRL, 0xF, 0xF, true));
}
template<int OFF>
__device__ __forceinline__ float swzx(float x) {
    return __int_as_float(__builtin_amdgcn_ds_swizzle(__float_as_int(x), OFF));
}
template<int P>
__device__ __forceinline__ float lane_xor(float x) {
    if constexpr (P == 0) return dppmov<0xB1>(x);      // quad_perm {1,0,3,2}
    else if constexpr (P == 1) return dppmov<0x4E>(x); // quad_perm {2,3,0,1}
    else if constexpr (P == 2) return swzx<0x101F>(x); // ds_swizzle xor 4
    else if constexpr (P == 3) return dppmov<0x128>(x);// row_ror:8 == xor 8
    else if constexpr (P == 4) return swzx<0x401F>(x); // ds_swizzle xor 16
    else return __shfl_xor(x, 32, 64);                 // cross-half
}

// ---------------- multilinear Horner evaluation over LDS coefficients ----------------
template<int L>
__device__ __forceinline__ float heval(const float* __restrict__ cf, const float* vx) {
    if constexpr (L == 2) {
        const float4 g = *reinterpret_cast<const float4*>(cf);   // uniform addr -> broadcast
        return (g.x + vx[0] * g.y) + vx[1] * (g.z + vx[0] * g.w);
    } else {
        return heval<L - 1>(cf, vx) + vx[L - 1] * heval<L - 1>(cf + (1 << (L - 1)), vx);
    }
}

template<int I>
__device__ __forceinline__ float qubit_eval(const float* __restrict__ coefI,
                                            const float* ca, const float* sa) {
    constexpr int V = NV(I);
    float vx[7];
    if constexpr (V > 0) vx[0] = ca[NQ - 1 - POSI(I, 0)];
    if constexpr (V > 1) vx[1] = ca[NQ - 1 - POSI(I, 1)];
    if constexpr (V > 2) vx[2] = ca[NQ - 1 - POSI(I, 2)];
    if constexpr (V > 3) vx[3] = ca[NQ - 1 - POSI(I, 3)];
    if constexpr (V > 4) vx[4] = ca[NQ - 1 - POSI(I, 4)];
    if constexpr (V > 5) vx[5] = ca[NQ - 1 - POSI(I, 5)];
    if constexpr (V > 6) vx[6] = ca[NQ - 1 - POSI(I, 6)];
    const float g = heval<V>(coefI, vx);
    float sp = 1.f;
    if constexpr ((VMASK(I) & (1 << 0)) != 0) sp *= sa[8];
    if constexpr ((VMASK(I) & (1 << 1)) != 0) sp *= sa[7];
    if constexpr ((VMASK(I) & (1 << 2)) != 0) sp *= sa[6];
    if constexpr ((VMASK(I) & (1 << 3)) != 0) sp *= sa[5];
    if constexpr ((VMASK(I) & (1 << 4)) != 0) sp *= sa[4];
    if constexpr ((VMASK(I) & (1 << 5)) != 0) sp *= sa[3];
    if constexpr ((VMASK(I) & (1 << 6)) != 0) sp *= sa[2];
    if constexpr ((VMASK(I) & (1 << 7)) != 0) sp *= sa[1];
    if constexpr ((VMASK(I) & (1 << 8)) != 0) sp *= sa[0];
    return sp * g;
}

// one cross-lane WHT butterfly stage over lane-bit S, on 4 register values
#define WHT_STAGE(S)                                              \
    {                                                             \
        const float sg = ((lane >> (S)) & 1) ? -1.f : 1.f;        \
        const float p0 = lane_xor<S>(r0);                         \
        const float p1 = lane_xor<S>(r1);                         \
        const float p2 = lane_xor<S>(r2);                         \
        const float p3 = lane_xor<S>(r3);                         \
        r0 = fmaf(sg, r0, p0);                                    \
        r1 = fmaf(sg, r1, p1);                                    \
        r2 = fmaf(sg, r2, p2);                                    \
        r3 = fmaf(sg, r3, p3);                                    \
    }

// ---------------- per-qubit block body (one wave): WHT + eval for qubit I ----------------
template<int I>
__device__ __forceinline__ void qubit_block(
    const float* __restrict__ x, float* __restrict__ out,
    const float2* sT2, float* sCoef, const int lane, const int bx)
{
    constexpr int Pi = NQ - 1 - I;

    // --- D(y) = sin(Theta(b|m_I) - Theta(b)) for y = (k<<6)|lane, k=0..3, in registers ---
    float r0, r1, r2, r3;
    {
        float* rr[1]; (void)rr;
        #define LOAD_D(K, DST)                                                        \
        {                                                                             \
            const int y  = ((K) << 6) | lane;                                         \
            const int b  = ((y >> Pi) << (Pi + 1)) | (y & ((1 << Pi) - 1));           \
            const int b2 = b | (1 << Pi);                                             \
            const float2 A = sT2[b];                                                  \
            const float2 B = sT2[b2];                                                 \
            DST = B.y * A.x - B.x * A.y;                                              \
        }
        LOAD_D(0, r0) LOAD_D(1, r1) LOAD_D(2, r2) LOAD_D(3, r3)
        #undef LOAD_D
    }

    // --- 256-point WHT: lane bits 0..5 cross-lane, k bits 6..7 in-register ---
    WHT_STAGE(0) WHT_STAGE(1) WHT_STAGE(2) WHT_STAGE(3) WHT_STAGE(4) WHT_STAGE(5)
    {
        const float t0 = r0 + r1, t1 = r0 - r1, t2 = r2 + r3, t3 = r2 - r3; // bit 6
        r0 = t0 + t2; r2 = t0 - t2; r1 = t1 + t3; r3 = t1 - t3;             // bit 7
    }

    // --- scatter the used coefficients straight into Horner order (constexpr perm) ---
    #define STORE_C(K, SRC)                                                  \
    {                                                                        \
        const int y = ((K) << 6) | lane;                                     \
        const unsigned short u = INVTAB.v[I][y];                             \
        if (u != 0xFFFF) sCoef[u] = (SRC) * (1.0f / 256.0f);                 \
    }
    STORE_C(0, r0) STORE_C(1, r1) STORE_C(2, r2) STORE_C(3, r3)
    #undef STORE_C
    __syncthreads();

    // --- one simulation per thread for qubit I ---
    const int sim = bx * 64 + lane;               // grid.x exact: 196*64 == 12544
    const int ox  = sim % 28;
    const int t1  = sim / 28;
    const int oy  = t1 % 28;
    const int img = t1 / 28;

    float ca[NQ], sa[NQ];
    #pragma unroll
    for (int q = 0; q < NQ; ++q) {
        const int ky = q / 3, kx = q % 3;
        const int yy = oy + ky - 1, xx = ox + kx - 1;
        float a = 0.f;
        if (yy >= 0 && yy < 28 && xx >= 0 && xx < 28)
            a = x[img * 784 + yy * 28 + xx];
        __sincosf(a, &sa[q], &ca[q]);
    }

    out[img * (NQ * 784) + I * 784 + oy * 28 + ox] = qubit_eval<I>(sCoef, ca, sa);
}

// ---------------- single fused kernel: grid (196, 9), 64 threads, blockIdx.y = qubit ----------------
__global__ __launch_bounds__(64) void quanv_fused(
    const float* __restrict__ x,    // [16][28][28]
    const float* __restrict__ w,    // [NREPS][NQ]
    float* __restrict__ out)        // [16][9][28][28]
{
    __shared__ float2 sT2[NB];                 // {cos Theta(b), sin Theta(b)}
    __shared__ __align__(16) float sCoef[128];
    const int lane = threadIdx.x;

    // --- Phase 1: Theta(b) phase table (8 entries per lane, fast sincos) ---
    #pragma unroll
    for (int k8 = 0; k8 < 8; ++k8) {
        const int b = k8 * 64 + lane;
        float th = 0.f;
        int cur = b;
        #pragma unroll
        for (int l = NREPS - 1; l >= 0; --l) {
            cur = csigma(cur);
            #pragma unroll
            for (int q = 0; q < NQ; ++q) {
                const float wq = 0.5f * w[l * NQ + q];
                th += ((cur >> (NQ - 1 - q)) & 1) ? wq : -wq;
            }
        }
        th -= 1.5707963267948966f * (float)__popc((unsigned)cur);
        float s, c;
        __sincosf(th, &s, &c);
        sT2[b] = make_float2(c, s);
    }
    __syncthreads();

    switch (blockIdx.y) {
        case 0: qubit_block<0>(x, out, sT2, sCoef, lane, blockIdx.x); break;
        case 1: qubit_block<1>(x, out, sT2, sCoef, lane, blockIdx.x); break;
        case 2: qubit_block<2>(x, out, sT2, sCoef, lane, blockIdx.x); break;
        case 3: qubit_block<3>(x, out, sT2, sCoef, lane, blockIdx.x); break;
        case 4: qubit_block<4>(x, out, sT2, sCoef, lane, blockIdx.x); break;
        case 5: qubit_block<5>(x, out, sT2, sCoef, lane, blockIdx.x); break;
        case 6: qubit_block<6>(x, out, sT2, sCoef, lane, blockIdx.x); break;
        case 7: qubit_block<7>(x, out, sT2, sCoef, lane, blockIdx.x); break;
        case 8: qubit_block<8>(x, out, sT2, sCoef, lane, blockIdx.x); break;
    }
}

extern "C" void kernel_launch(void* const* d_in, const int* in_sizes, int n_in,
                              void* d_out, int out_size, void* d_ws, size_t ws_size,
                              hipStream_t stream) {
    const float* x = (const float*)d_in[0];   // 16*1*28*28 fp32
    const float* w = (const float*)d_in[1];   // NREPS*NQ fp32
    float* out = (float*)d_out;               // 16*9*28*28 fp32
    (void)d_ws; (void)ws_size; (void)in_sizes; (void)n_in; (void)out_size;

    quanv_fused<<<dim3(NSIMS / 64, NQ), 64, 0, stream>>>(x, w, out);
}